// Round 3
// baseline (105.936 us; speedup 1.0000x reference)
//
#include <hip/hip_runtime.h>
#include <hip/hip_bf16.h>

#define NB 64    // batch
#define NT 128   // tokens (seq)
#define NE 4     // experts
#define ND 128   // model dim
#define NK 512   // ffn hidden dim
#define MH 32    // batch rows per block (half)

typedef __attribute__((ext_vector_type(8))) short bf16x8;
typedef __attribute__((ext_vector_type(4))) float f32x4;

__device__ __forceinline__ short f2bf(float f) {
    union { __hip_bfloat16 b; short s; } u;
    u.b = __float2bfloat16(f);
    return u.s;
}

__device__ __forceinline__ bf16x8 cvt8(const float* f) {
    bf16x8 r;
    #pragma unroll
    for (int j = 0; j < 8; ++j) r[j] = f2bf(f[j]);
    return r;
}

__device__ __forceinline__ float gelu_erf(float x) {
    return 0.5f * x * (1.0f + erff(x * 0.70710678118654752f));
}

// ---------------- router: one wave per token (4 tokens per wave via loop) ----
__global__ __launch_bounds__(256)
void moe_gates(const float* __restrict__ x,
               const float* __restrict__ rw,
               const float* __restrict__ rb,
               float* __restrict__ gates_ws,
               float* __restrict__ aux_partial)
{
    const int tid  = threadIdx.x;
    const int lane = tid & 63;
    const int wave = tid >> 6;
    __shared__ float waux[4];

    const float4 rw0 = *(const float4*)(rw + lane * 4);
    const float4 rw1 = *(const float4*)(rw + (64 + lane) * 4);
    const float4 rbv = *(const float4*)rb;

    float aux = 0.f;
    #pragma unroll
    for (int i = 0; i < 4; ++i) {
        const int tok = (blockIdx.x * 4 + wave) * 4 + i;       // b*NT + t
        const float x0 = x[tok * ND + lane];
        const float x1 = x[tok * ND + 64 + lane];
        float p0 = x0 * rw0.x + x1 * rw1.x;
        float p1 = x0 * rw0.y + x1 * rw1.y;
        float p2 = x0 * rw0.z + x1 * rw1.z;
        float p3 = x0 * rw0.w + x1 * rw1.w;
        #pragma unroll
        for (int off = 32; off > 0; off >>= 1) {
            p0 += __shfl_xor(p0, off);
            p1 += __shfl_xor(p1, off);
            p2 += __shfl_xor(p2, off);
            p3 += __shfl_xor(p3, off);
        }
        if (lane == 0) {
            p0 = fmaxf(p0 + rbv.x, 0.f);
            p1 = fmaxf(p1 + rbv.y, 0.f);
            p2 = fmaxf(p2 + rbv.z, 0.f);
            p3 = fmaxf(p3 + rbv.w, 0.f);
            const float s   = p0 + p1 + p2 + p3;
            const float inv = 1.f / (s + 1e-9f);
            float4 g; g.x = p0 * inv; g.y = p1 * inv; g.z = p2 * inv; g.w = p3 * inv;
            *(float4*)(gates_ws + tok * NE) = g;
            aux += s * inv;
        }
    }
    if (lane == 0) waux[wave] = aux;
    __syncthreads();
    if (tid == 0)
        aux_partial[blockIdx.x] = waux[0] + waux[1] + waux[2] + waux[3];
}

// ---------------- main: one block per (t, e, batch-half); 4 waves ------------
// Explicit 2-deep register prefetch of weight gathers to maximize MLP.
__global__ __launch_bounds__(256)
void moe_main(const float* __restrict__ x,
              const float* __restrict__ w1,
              const float* __restrict__ b1,
              const float* __restrict__ w2,
              const float* __restrict__ b2,
              const float* __restrict__ gates_ws,
              float* __restrict__ ws)
{
    const int bid  = blockIdx.x;
    const int h    = bid >> 9;          // twins (s, s+512) -> same XCD (mod 8)
    const int s    = bid & 511;
    const int t    = s >> 2;
    const int e    = s & 3;
    const int tid  = threadIdx.x;
    const int lane = tid & 63;
    const int wave = tid >> 6;
    const int l15  = lane & 15;
    const int l4   = lane >> 4;

    __shared__ short Hs[MH][NK + 8];    // 32 x 520 bf16 bits = 33,280 B
    __shared__ float gate_s[MH];

    if (tid < MH)
        gate_s[tid] = gates_ws[((h * MH + tid) * NT + t) * NE + e];

    // ---------------- GEMM1: wave owns 128-col N-stripe ----------------
    const float* W1 = w1 + (size_t)((t * NE + e) * ND) * NK;  // [ND][NK]
    const float* B1 = b1 + (t * NE + e) * NK;
    const int n0 = wave * 128;

    // Preload ALL A fragments (x) for GEMM1: 2 m-frags x 4 ks
    bf16x8 afr[4][2];
    {
        float4 xa[4][2][2];
        #pragma unroll
        for (int ks = 0; ks < 4; ++ks) {
            const int d0 = ks * 32 + l4 * 8;
            #pragma unroll
            for (int m = 0; m < 2; ++m) {
                const float* xp = x + (size_t)((h * MH + m * 16 + l15) * NT + t) * ND + d0;
                xa[ks][m][0] = *(const float4*)xp;
                xa[ks][m][1] = *(const float4*)(xp + 4);
            }
        }
        #pragma unroll
        for (int ks = 0; ks < 4; ++ks)
            #pragma unroll
            for (int m = 0; m < 2; ++m)
                afr[ks][m] = cvt8((const float*)&xa[ks][m][0]);
    }

    f32x4 acc[2][8];
    #pragma unroll
    for (int m = 0; m < 2; ++m)
        #pragma unroll
        for (int n = 0; n < 8; ++n) acc[m][n] = (f32x4){0.f, 0.f, 0.f, 0.f};

    // flattened (ks, nt) loop with 2-deep weight prefetch
    {
        const float* wbase = W1 + (size_t)(l4 * 8) * NK + n0 + l15;
        float wbuf[2][8];
        #pragma unroll
        for (int j = 0; j < 8; ++j) wbuf[0][j] = wbase[(size_t)j * NK];

        #pragma unroll
        for (int p = 0; p < 32; ++p) {
            const int ks = p >> 3, nt = p & 7;
            if (p < 31) {
                const int p1 = p + 1;
                const int ks1 = p1 >> 3, nt1 = p1 & 7;
                const float* wp = wbase + (size_t)(ks1 * 32) * NK + nt1 * 16;
                #pragma unroll
                for (int j = 0; j < 8; ++j) wbuf[p1 & 1][j] = wp[(size_t)j * NK];
            }
            const bf16x8 bfr = cvt8(wbuf[p & 1]);
            acc[0][nt] = __builtin_amdgcn_mfma_f32_16x16x32_bf16(afr[ks][0], bfr, acc[0][nt], 0, 0, 0);
            acc[1][nt] = __builtin_amdgcn_mfma_f32_16x16x32_bf16(afr[ks][1], bfr, acc[1][nt], 0, 0, 0);
        }
    }

    // bias + exact-erf gelu -> bf16 H in LDS
    #pragma unroll
    for (int nt = 0; nt < 8; ++nt) {
        const int n = n0 + nt * 16 + l15;
        const float bb = B1[n];
        #pragma unroll
        for (int m = 0; m < 2; ++m) {
            const int row = m * 16 + l4 * 4;
            #pragma unroll
            for (int r = 0; r < 4; ++r) {
                const float hh = acc[m][nt][r] + bb;
                Hs[row + r][n] = f2bf(gelu_erf(hh));
            }
        }
    }
    __syncthreads();

    // ---------------- GEMM2: wave owns 32 output cols ----------------
    const float* W2 = w2 + (size_t)((t * NE + e) * NK) * ND;  // [NK][ND]
    const float* B2 = b2 + (t * NE + e) * ND;
    const int c0 = wave * 32;

    f32x4 acc2[2][2];
    #pragma unroll
    for (int m = 0; m < 2; ++m)
        #pragma unroll
        for (int n = 0; n < 2; ++n) acc2[m][n] = (f32x4){0.f, 0.f, 0.f, 0.f};

    {
        const float* w2base = W2 + (size_t)(l4 * 8) * ND + c0 + l15;
        float wb2[2][8];
        #pragma unroll
        for (int j = 0; j < 8; ++j) wb2[0][j] = w2base[(size_t)j * ND];

        bf16x8 a2[2];
        #pragma unroll
        for (int p = 0; p < 32; ++p) {
            const int ks = p >> 1, nt = p & 1;
            if (nt == 0) {
                const int k0 = ks * 32 + l4 * 8;
                a2[0] = *(const bf16x8*)(&Hs[l15][k0]);
                a2[1] = *(const bf16x8*)(&Hs[16 + l15][k0]);
            }
            if (p < 31) {
                const int p1 = p + 1;
                const int ks1 = p1 >> 1, nt1 = p1 & 1;
                const float* wp = w2base + (size_t)(ks1 * 32) * ND + nt1 * 16;
                #pragma unroll
                for (int j = 0; j < 8; ++j) wb2[p1 & 1][j] = wp[(size_t)j * ND];
            }
            const bf16x8 bfr = cvt8(wb2[p & 1]);
            acc2[0][nt] = __builtin_amdgcn_mfma_f32_16x16x32_bf16(a2[0], bfr, acc2[0][nt], 0, 0, 0);
            acc2[1][nt] = __builtin_amdgcn_mfma_f32_16x16x32_bf16(a2[1], bfr, acc2[1][nt], 0, 0, 0);
        }
    }

    // gate-weighted epilogue -> ws[e][b][t][d]
    #pragma unroll
    for (int nt = 0; nt < 2; ++nt) {
        const int c = c0 + nt * 16 + l15;
        const float bb = B2[c];
        #pragma unroll
        for (int m = 0; m < 2; ++m) {
            #pragma unroll
            for (int r = 0; r < 4; ++r) {
                const int bl = m * 16 + l4 * 4 + r;
                const int b  = h * MH + bl;
                const float v = (acc2[m][nt][r] + bb) * gate_s[bl];
                ws[(size_t)(e * NB * NT + b * NT + t) * ND + c] = v;
            }
        }
    }
}

// ---------------- reduce 4 expert contributions + finalize aux ---------------
__global__ __launch_bounds__(256)
void moe_reduce(const float* __restrict__ ws,
                const float* __restrict__ aux_partial,
                float* __restrict__ out)
{
    const int i = blockIdx.x * blockDim.x + threadIdx.x;
    const int stride = NB * NT * ND / 4;
    const float4* w = (const float4*)ws;
    const float4 a = w[i];
    const float4 b = w[i + stride];
    const float4 c = w[i + 2 * stride];
    const float4 d = w[i + 3 * stride];
    float4 r;
    r.x = a.x + b.x + c.x + d.x;
    r.y = a.y + b.y + c.y + d.y;
    r.z = a.z + b.z + c.z + d.z;
    r.w = a.w + b.w + c.w + d.w;
    ((float4*)out)[i] = r;

    if (blockIdx.x == 0) {
        const int tid = threadIdx.x;
        float s = aux_partial[tid] + aux_partial[tid + 256];
        #pragma unroll
        for (int off = 32; off > 0; off >>= 1) s += __shfl_xor(s, off);
        __shared__ float wsum[4];
        if ((tid & 63) == 0) wsum[tid >> 6] = s;
        __syncthreads();
        if (tid == 0)
            out[NB * NT * ND] = (wsum[0] + wsum[1] + wsum[2] + wsum[3]) *
                                (0.01f / (NB * NT));
    }
}

// ---------------- fallback (ws too small): self-contained, atomics -----------
__global__ __launch_bounds__(256, 2)
void moe_main_fb(const float* __restrict__ x,
                 const float* __restrict__ w1,
                 const float* __restrict__ b1,
                 const float* __restrict__ w2,
                 const float* __restrict__ b2,
                 const float* __restrict__ rw,
                 const float* __restrict__ rb,
                 float* __restrict__ out)
{
    const int blk  = blockIdx.x;
    const int t    = blk >> 2;
    const int e    = blk & 3;
    const int tid  = threadIdx.x;
    const int lane = tid & 63;
    const int wave = tid >> 6;
    const int l15  = lane & 15;
    const int l4   = lane >> 4;

    __shared__ short Hs[NB][NK + 8];
    __shared__ float gate_s[NB];

    if (tid < NB) {
        const int b = tid;
        const float* xr = x + (b * NT + t) * ND;
        float l0 = rb[0], l1 = rb[1], l2 = rb[2], l3 = rb[3];
        #pragma unroll 8
        for (int d = 0; d < ND; ++d) {
            const float xv = xr[d];
            const float* w = rw + d * NE;
            l0 += xv * w[0]; l1 += xv * w[1]; l2 += xv * w[2]; l3 += xv * w[3];
        }
        l0 = fmaxf(l0, 0.f); l1 = fmaxf(l1, 0.f); l2 = fmaxf(l2, 0.f); l3 = fmaxf(l3, 0.f);
        const float ss  = l0 + l1 + l2 + l3;
        const float inv = 1.f / (ss + 1e-9f);
        const float ge  = (e == 0) ? l0 : (e == 1) ? l1 : (e == 2) ? l2 : l3;
        gate_s[b] = ge * inv;
        if (e == 0) {
            float aux = ss * inv;
            #pragma unroll
            for (int off = 32; off > 0; off >>= 1) aux += __shfl_down(aux, off);
            if (lane == 0) atomicAdd(out + NB * NT * ND, aux * (0.01f / (NB * NT)));
        }
    }
    __syncthreads();

    const float* W1 = w1 + (size_t)((t * NE + e) * ND) * NK;
    const float* B1 = b1 + (t * NE + e) * NK;
    const int n0 = wave * 128;

    f32x4 acc[4][8];
    #pragma unroll
    for (int m = 0; m < 4; ++m)
        #pragma unroll
        for (int n = 0; n < 8; ++n) acc[m][n] = (f32x4){0.f, 0.f, 0.f, 0.f};

    #pragma unroll
    for (int ks = 0; ks < 4; ++ks) {
        const int d0 = ks * 32 + l4 * 8;
        bf16x8 afr[4];
        #pragma unroll
        for (int m = 0; m < 4; ++m) {
            const int b = m * 16 + l15;
            const float* xp = x + (b * NT + t) * ND + d0;
            float xf[8];
            *(float4*)&xf[0] = *(const float4*)(xp);
            *(float4*)&xf[4] = *(const float4*)(xp + 4);
            afr[m] = cvt8(xf);
        }
        #pragma unroll
        for (int nt = 0; nt < 8; ++nt) {
            const int n = n0 + nt * 16 + l15;
            const float* wp = W1 + (size_t)d0 * NK + n;
            float wf[8];
            #pragma unroll
            for (int j = 0; j < 8; ++j) wf[j] = wp[(size_t)j * NK];
            const bf16x8 bfr = cvt8(wf);
            #pragma unroll
            for (int m = 0; m < 4; ++m)
                acc[m][nt] = __builtin_amdgcn_mfma_f32_16x16x32_bf16(afr[m], bfr, acc[m][nt], 0, 0, 0);
        }
    }

    #pragma unroll
    for (int nt = 0; nt < 8; ++nt) {
        const int n = n0 + nt * 16 + l15;
        const float bb = B1[n];
        #pragma unroll
        for (int m = 0; m < 4; ++m) {
            const int row = m * 16 + l4 * 4;
            #pragma unroll
            for (int r = 0; r < 4; ++r) {
                const float hh = acc[m][nt][r] + bb;
                Hs[row + r][n] = f2bf(gelu_erf(hh));
            }
        }
    }
    __syncthreads();

    const float* W2 = w2 + (size_t)((t * NE + e) * NK) * ND;
    const float* B2 = b2 + (t * NE + e) * ND;
    const int c0 = wave * 32;

    f32x4 acc2[4][2];
    #pragma unroll
    for (int m = 0; m < 4; ++m)
        #pragma unroll
        for (int n = 0; n < 2; ++n) acc2[m][n] = (f32x4){0.f, 0.f, 0.f, 0.f};

    #pragma unroll 4
    for (int ks = 0; ks < 16; ++ks) {
        const int k0 = ks * 32 + l4 * 8;
        bf16x8 afr[4];
        #pragma unroll
        for (int m = 0; m < 4; ++m)
            afr[m] = *(const bf16x8*)(&Hs[m * 16 + l15][k0]);
        #pragma unroll
        for (int nt = 0; nt < 2; ++nt) {
            const int c = c0 + nt * 16 + l15;
            const float* wp = W2 + (size_t)k0 * ND + c;
            float wf[8];
            #pragma unroll
            for (int j = 0; j < 8; ++j) wf[j] = wp[(size_t)j * ND];
            const bf16x8 bfr = cvt8(wf);
            #pragma unroll
            for (int m = 0; m < 4; ++m)
                acc2[m][nt] = __builtin_amdgcn_mfma_f32_16x16x32_bf16(afr[m], bfr, acc2[m][nt], 0, 0, 0);
        }
    }

    #pragma unroll
    for (int nt = 0; nt < 2; ++nt) {
        const int c = c0 + nt * 16 + l15;
        const float bb = B2[c];
        #pragma unroll
        for (int m = 0; m < 4; ++m) {
            #pragma unroll
            for (int r = 0; r < 4; ++r) {
                const int b = m * 16 + l4 * 4 + r;
                const float v = (acc2[m][nt][r] + bb) * gate_s[b];
                atomicAdd(out + (size_t)(b * NT + t) * ND + c, v);
            }
        }
    }
}

extern "C" void kernel_launch(void* const* d_in, const int* in_sizes, int n_in,
                              void* d_out, int out_size, void* d_ws, size_t ws_size,
                              hipStream_t stream) {
    const float* x  = (const float*)d_in[0];
    const float* w1 = (const float*)d_in[1];
    const float* b1 = (const float*)d_in[2];
    const float* w2 = (const float*)d_in[3];
    const float* b2 = (const float*)d_in[4];
    const float* rw = (const float*)d_in[5];
    const float* rb = (const float*)d_in[6];
    float* out = (float*)d_out;

    const size_t contrib_elems = (size_t)NE * NB * NT * ND;           // 16 MiB
    const size_t gates_elems   = (size_t)NB * NT * NE;
    const size_t aux_elems     = 512;
    const size_t ws_need = (contrib_elems + gates_elems + aux_elems) * sizeof(float);

    if (ws_size >= ws_need) {
        float* contrib = (float*)d_ws;
        float* gates   = contrib + contrib_elems;
        float* auxp    = gates + gates_elems;

        moe_gates<<<512, 256, 0, stream>>>(x, rw, rb, gates, auxp);
        moe_main<<<NT * NE * 2, 256, 0, stream>>>(x, w1, b1, w2, b2, gates, contrib);
        moe_reduce<<<(NB * NT * ND / 4) / 256, 256, 0, stream>>>(contrib, auxp, out);
    } else {
        hipMemsetAsync(d_out, 0, (size_t)(NB * NT * ND + 1) * sizeof(float), stream);
        moe_main_fb<<<NT * NE, 256, 0, stream>>>(x, w1, b1, w2, b2, rw, rb, out);
    }
}

// Round 6
// 70.714 us; speedup vs baseline: 1.4981x; 1.4981x over previous
//
#include <hip/hip_runtime.h>
#include <hip/hip_bf16.h>

#define NB 64    // batch
#define NT 128   // tokens (seq)
#define NE 4     // experts
#define ND 128   // model dim
#define NK 512   // ffn hidden dim

typedef __attribute__((ext_vector_type(8))) short bf16x8;
typedef __attribute__((ext_vector_type(4))) float f32x4;

__device__ __forceinline__ short f2bf(float f) {
    union { __hip_bfloat16 b; short s; } u;
    u.b = __float2bfloat16(f);
    return u.s;
}

__device__ __forceinline__ bf16x8 cvt8(const float* f) {
    bf16x8 r;
    #pragma unroll
    for (int j = 0; j < 8; ++j) r[j] = f2bf(f[j]);
    return r;
}

__device__ __forceinline__ float gelu_erf(float x) {
    return 0.5f * x * (1.0f + erff(x * 0.70710678118654752f));
}

// ---------------- router: one wave per token (4 tokens per wave via loop) ----
__global__ __launch_bounds__(256)
void moe_gates(const float* __restrict__ x,
               const float* __restrict__ rw,
               const float* __restrict__ rb,
               float* __restrict__ gates_ws,
               float* __restrict__ aux_partial)
{
    const int tid  = threadIdx.x;
    const int lane = tid & 63;
    const int wave = tid >> 6;
    __shared__ float waux[4];

    const float4 rw0 = *(const float4*)(rw + lane * 4);
    const float4 rw1 = *(const float4*)(rw + (64 + lane) * 4);
    const float4 rbv = *(const float4*)rb;

    float aux = 0.f;
    #pragma unroll
    for (int i = 0; i < 4; ++i) {
        const int tok = (blockIdx.x * 4 + wave) * 4 + i;       // b*NT + t
        const float x0 = x[tok * ND + lane];
        const float x1 = x[tok * ND + 64 + lane];
        float p0 = x0 * rw0.x + x1 * rw1.x;
        float p1 = x0 * rw0.y + x1 * rw1.y;
        float p2 = x0 * rw0.z + x1 * rw1.z;
        float p3 = x0 * rw0.w + x1 * rw1.w;
        #pragma unroll
        for (int off = 32; off > 0; off >>= 1) {
            p0 += __shfl_xor(p0, off);
            p1 += __shfl_xor(p1, off);
            p2 += __shfl_xor(p2, off);
            p3 += __shfl_xor(p3, off);
        }
        if (lane == 0) {
            p0 = fmaxf(p0 + rbv.x, 0.f);
            p1 = fmaxf(p1 + rbv.y, 0.f);
            p2 = fmaxf(p2 + rbv.z, 0.f);
            p3 = fmaxf(p3 + rbv.w, 0.f);
            const float s   = p0 + p1 + p2 + p3;
            const float inv = 1.f / (s + 1e-9f);
            float4 g; g.x = p0 * inv; g.y = p1 * inv; g.z = p2 * inv; g.w = p3 * inv;
            *(float4*)(gates_ws + tok * NE) = g;
            aux += s * inv;
        }
    }
    if (lane == 0) waux[wave] = aux;
    __syncthreads();
    if (tid == 0)
        aux_partial[blockIdx.x] = waux[0] + waux[1] + waux[2] + waux[3];
}

// ---------------- main: one block per (t, e); M=64; 4 waves ------------------
// All 512 blocks co-resident (2/CU, LDS-capped) -> each weight byte fetched
// once. Depth-4 register prefetch; CONSUME slot before refilling it.
__global__ __launch_bounds__(256, 2)
void moe_main(const float* __restrict__ x,
              const float* __restrict__ w1,
              const float* __restrict__ b1,
              const float* __restrict__ w2,
              const float* __restrict__ b2,
              const float* __restrict__ gates_ws,
              float* __restrict__ ws)
{
    const int bid  = blockIdx.x;
    const int t    = bid >> 2;
    const int e    = bid & 3;
    const int tid  = threadIdx.x;
    const int lane = tid & 63;
    const int wave = tid >> 6;
    const int l15  = lane & 15;
    const int l4   = lane >> 4;

    __shared__ short Hs[NB][NK + 8];    // 64 x 520 bf16 bits = 66,560 B
    __shared__ float gate_s[NB];

    if (tid < NB)
        gate_s[tid] = gates_ws[(tid * NT + t) * NE + e];

    // ---------------- GEMM1: X[64x128] * W1[128x512]; wave owns 128 cols -----
    const float* W1 = w1 + (size_t)((t * NE + e) * ND) * NK;  // [ND][NK]
    const float* B1 = b1 + (t * NE + e) * NK;
    const int n0 = wave * 128;

    f32x4 acc[4][8];
    #pragma unroll
    for (int m = 0; m < 4; ++m)
        #pragma unroll
        for (int n = 0; n < 8; ++n) acc[m][n] = (f32x4){0.f, 0.f, 0.f, 0.f};

    {
        const float* wbase = W1 + (size_t)(l4 * 8) * NK + n0 + l15;
        float wbuf[4][8];
        // prologue: prefetch p = 0..3 (all ks=0, nt=q)
        #pragma unroll
        for (int q = 0; q < 4; ++q) {
            const float* wp = wbase + q * 16;
            #pragma unroll
            for (int j = 0; j < 8; ++j) wbuf[q][j] = wp[(size_t)j * NK];
        }

        bf16x8 afr[4];
        #pragma unroll
        for (int p = 0; p < 32; ++p) {
            const int ks = p >> 3, nt = p & 7;
            if (nt == 0) {
                const int d0 = ks * 32 + l4 * 8;
                #pragma unroll
                for (int m = 0; m < 4; ++m) {
                    const float* xp = x + (size_t)((m * 16 + l15) * NT + t) * ND + d0;
                    float xf[8];
                    *(float4*)&xf[0] = *(const float4*)(xp);
                    *(float4*)&xf[4] = *(const float4*)(xp + 4);
                    afr[m] = cvt8(xf);
                }
            }
            // CONSUME slot p&3 first...
            const bf16x8 bfr = cvt8(wbuf[p & 3]);
            // ...then refill the dead slot with iteration p+4's weights
            if (p < 28) {
                const int p4 = p + 4;
                const int ks4 = p4 >> 3, nt4 = p4 & 7;
                const float* wp = wbase + (size_t)(ks4 * 32) * NK + nt4 * 16;
                #pragma unroll
                for (int j = 0; j < 8; ++j) wbuf[p4 & 3][j] = wp[(size_t)j * NK];
            }
            #pragma unroll
            for (int m = 0; m < 4; ++m)
                acc[m][nt] = __builtin_amdgcn_mfma_f32_16x16x32_bf16(afr[m], bfr, acc[m][nt], 0, 0, 0);
        }
    }

    // bias + exact-erf gelu -> bf16 H in LDS
    #pragma unroll
    for (int nt = 0; nt < 8; ++nt) {
        const int n = n0 + nt * 16 + l15;
        const float bb = B1[n];
        #pragma unroll
        for (int m = 0; m < 4; ++m) {
            const int row = m * 16 + l4 * 4;
            #pragma unroll
            for (int r = 0; r < 4; ++r) {
                const float hh = acc[m][nt][r] + bb;
                Hs[row + r][n] = f2bf(gelu_erf(hh));
            }
        }
    }
    __syncthreads();

    // ---------------- GEMM2: H[64x512] * W2[512x128]; wave owns 32 cols ------
    const float* W2 = w2 + (size_t)((t * NE + e) * NK) * ND;  // [NK][ND]
    const float* B2 = b2 + (t * NE + e) * ND;
    const int c0 = wave * 32;

    f32x4 acc2[4][2];
    #pragma unroll
    for (int m = 0; m < 4; ++m)
        #pragma unroll
        for (int n = 0; n < 2; ++n) acc2[m][n] = (f32x4){0.f, 0.f, 0.f, 0.f};

    {
        const float* w2base = W2 + (size_t)(l4 * 8) * ND + c0 + l15;
        float wb2[4][8];
        // prologue: prefetch p = 0..3 (ks=0,1; nt=0,1)
        #pragma unroll
        for (int q = 0; q < 4; ++q) {
            const int ksq = q >> 1, ntq = q & 1;
            const float* wp = w2base + (size_t)(ksq * 32) * ND + ntq * 16;
            #pragma unroll
            for (int j = 0; j < 8; ++j) wb2[q][j] = wp[(size_t)j * ND];
        }

        bf16x8 a2[4];
        #pragma unroll
        for (int p = 0; p < 32; ++p) {
            const int ks = p >> 1, nt = p & 1;
            if (nt == 0) {
                const int k0 = ks * 32 + l4 * 8;
                #pragma unroll
                for (int m = 0; m < 4; ++m)
                    a2[m] = *(const bf16x8*)(&Hs[m * 16 + l15][k0]);
            }
            // CONSUME slot p&3 first...
            const bf16x8 bfr = cvt8(wb2[p & 3]);
            // ...then refill the dead slot with iteration p+4's weights
            if (p < 28) {
                const int p4 = p + 4;
                const int ks4 = p4 >> 1, nt4 = p4 & 1;
                const float* wp = w2base + (size_t)(ks4 * 32) * ND + nt4 * 16;
                #pragma unroll
                for (int j = 0; j < 8; ++j) wb2[p4 & 3][j] = wp[(size_t)j * ND];
            }
            #pragma unroll
            for (int m = 0; m < 4; ++m)
                acc2[m][nt] = __builtin_amdgcn_mfma_f32_16x16x32_bf16(a2[m], bfr, acc2[m][nt], 0, 0, 0);
        }
    }

    // gate-weighted epilogue -> ws[e][b][t][d]
    #pragma unroll
    for (int nt = 0; nt < 2; ++nt) {
        const int c = c0 + nt * 16 + l15;
        const float bb = B2[c];
        #pragma unroll
        for (int m = 0; m < 4; ++m) {
            #pragma unroll
            for (int r = 0; r < 4; ++r) {
                const int b = m * 16 + l4 * 4 + r;
                const float v = (acc2[m][nt][r] + bb) * gate_s[b];
                ws[(size_t)(e * NB * NT + b * NT + t) * ND + c] = v;
            }
        }
    }
}

// ---------------- reduce 4 expert contributions + finalize aux ---------------
__global__ __launch_bounds__(256)
void moe_reduce(const float* __restrict__ ws,
                const float* __restrict__ aux_partial,
                float* __restrict__ out)
{
    const int i = blockIdx.x * blockDim.x + threadIdx.x;
    const int stride = NB * NT * ND / 4;
    const float4* w = (const float4*)ws;
    const float4 a = w[i];
    const float4 b = w[i + stride];
    const float4 c = w[i + 2 * stride];
    const float4 d = w[i + 3 * stride];
    float4 r;
    r.x = a.x + b.x + c.x + d.x;
    r.y = a.y + b.y + c.y + d.y;
    r.z = a.z + b.z + c.z + d.z;
    r.w = a.w + b.w + c.w + d.w;
    ((float4*)out)[i] = r;

    if (blockIdx.x == 0) {
        const int tid = threadIdx.x;
        float s = aux_partial[tid] + aux_partial[tid + 256];
        #pragma unroll
        for (int off = 32; off > 0; off >>= 1) s += __shfl_xor(s, off);
        __shared__ float wsum[4];
        if ((tid & 63) == 0) wsum[tid >> 6] = s;
        __syncthreads();
        if (tid == 0)
            out[NB * NT * ND] = (wsum[0] + wsum[1] + wsum[2] + wsum[3]) *
                                (0.01f / (NB * NT));
    }
}

// ---------------- fallback (ws too small): self-contained, atomics -----------
__global__ __launch_bounds__(256, 2)
void moe_main_fb(const float* __restrict__ x,
                 const float* __restrict__ w1,
                 const float* __restrict__ b1,
                 const float* __restrict__ w2,
                 const float* __restrict__ b2,
                 const float* __restrict__ rw,
                 const float* __restrict__ rb,
                 float* __restrict__ out)
{
    const int blk  = blockIdx.x;
    const int t    = blk >> 2;
    const int e    = blk & 3;
    const int tid  = threadIdx.x;
    const int lane = tid & 63;
    const int wave = tid >> 6;
    const int l15  = lane & 15;
    const int l4   = lane >> 4;

    __shared__ short Hs[NB][NK + 8];
    __shared__ float gate_s[NB];

    if (tid < NB) {
        const int b = tid;
        const float* xr = x + (b * NT + t) * ND;
        float l0 = rb[0], l1 = rb[1], l2 = rb[2], l3 = rb[3];
        #pragma unroll 8
        for (int d = 0; d < ND; ++d) {
            const float xv = xr[d];
            const float* w = rw + d * NE;
            l0 += xv * w[0]; l1 += xv * w[1]; l2 += xv * w[2]; l3 += xv * w[3];
        }
        l0 = fmaxf(l0, 0.f); l1 = fmaxf(l1, 0.f); l2 = fmaxf(l2, 0.f); l3 = fmaxf(l3, 0.f);
        const float ss  = l0 + l1 + l2 + l3;
        const float inv = 1.f / (ss + 1e-9f);
        const float ge  = (e == 0) ? l0 : (e == 1) ? l1 : (e == 2) ? l2 : l3;
        gate_s[b] = ge * inv;
        if (e == 0) {
            float aux = ss * inv;
            #pragma unroll
            for (int off = 32; off > 0; off >>= 1) aux += __shfl_down(aux, off);
            if (lane == 0) atomicAdd(out + NB * NT * ND, aux * (0.01f / (NB * NT)));
        }
    }
    __syncthreads();

    const float* W1 = w1 + (size_t)((t * NE + e) * ND) * NK;
    const float* B1 = b1 + (t * NE + e) * NK;
    const int n0 = wave * 128;

    f32x4 acc[4][8];
    #pragma unroll
    for (int m = 0; m < 4; ++m)
        #pragma unroll
        for (int n = 0; n < 8; ++n) acc[m][n] = (f32x4){0.f, 0.f, 0.f, 0.f};

    #pragma unroll
    for (int ks = 0; ks < 4; ++ks) {
        const int d0 = ks * 32 + l4 * 8;
        bf16x8 afr[4];
        #pragma unroll
        for (int m = 0; m < 4; ++m) {
            const int b = m * 16 + l15;
            const float* xp = x + (b * NT + t) * ND + d0;
            float xf[8];
            *(float4*)&xf[0] = *(const float4*)(xp);
            *(float4*)&xf[4] = *(const float4*)(xp + 4);
            afr[m] = cvt8(xf);
        }
        #pragma unroll
        for (int nt = 0; nt < 8; ++nt) {
            const int n = n0 + nt * 16 + l15;
            const float* wp = W1 + (size_t)d0 * NK + n;
            float wf[8];
            #pragma unroll
            for (int j = 0; j < 8; ++j) wf[j] = wp[(size_t)j * NK];
            const bf16x8 bfr = cvt8(wf);
            #pragma unroll
            for (int m = 0; m < 4; ++m)
                acc[m][nt] = __builtin_amdgcn_mfma_f32_16x16x32_bf16(afr[m], bfr, acc[m][nt], 0, 0, 0);
        }
    }

    #pragma unroll
    for (int nt = 0; nt < 8; ++nt) {
        const int n = n0 + nt * 16 + l15;
        const float bb = B1[n];
        #pragma unroll
        for (int m = 0; m < 4; ++m) {
            const int row = m * 16 + l4 * 4;
            #pragma unroll
            for (int r = 0; r < 4; ++r) {
                const float hh = acc[m][nt][r] + bb;
                Hs[row + r][n] = f2bf(gelu_erf(hh));
            }
        }
    }
    __syncthreads();

    const float* W2 = w2 + (size_t)((t * NE + e) * NK) * ND;
    const float* B2 = b2 + (t * NE + e) * ND;
    const int c0 = wave * 32;

    f32x4 acc2[4][2];
    #pragma unroll
    for (int m = 0; m < 4; ++m)
        #pragma unroll
        for (int n = 0; n < 2; ++n) acc2[m][n] = (f32x4){0.f, 0.f, 0.f, 0.f};

    #pragma unroll 4
    for (int ks = 0; ks < 16; ++ks) {
        const int k0 = ks * 32 + l4 * 8;
        bf16x8 afr[4];
        #pragma unroll
        for (int m = 0; m < 4; ++m)
            afr[m] = *(const bf16x8*)(&Hs[m * 16 + l15][k0]);
        #pragma unroll
        for (int nt = 0; nt < 2; ++nt) {
            const int c = c0 + nt * 16 + l15;
            const float* wp = W2 + (size_t)k0 * ND + c;
            float wf[8];
            #pragma unroll
            for (int j = 0; j < 8; ++j) wf[j] = wp[(size_t)j * ND];
            const bf16x8 bfr = cvt8(wf);
            #pragma unroll
            for (int m = 0; m < 4; ++m)
                acc2[m][nt] = __builtin_amdgcn_mfma_f32_16x16x32_bf16(afr[m], bfr, acc2[m][nt], 0, 0, 0);
        }
    }

    #pragma unroll
    for (int nt = 0; nt < 2; ++nt) {
        const int c = c0 + nt * 16 + l15;
        const float bb = B2[c];
        #pragma unroll
        for (int m = 0; m < 4; ++m) {
            #pragma unroll
            for (int r = 0; r < 4; ++r) {
                const int b = m * 16 + l4 * 4 + r;
                const float v = (acc2[m][nt][r] + bb) * gate_s[b];
                atomicAdd(out + (size_t)(b * NT + t) * ND + c, v);
            }
        }
    }
}

extern "C" void kernel_launch(void* const* d_in, const int* in_sizes, int n_in,
                              void* d_out, int out_size, void* d_ws, size_t ws_size,
                              hipStream_t stream) {
    const float* x  = (const float*)d_in[0];
    const float* w1 = (const float*)d_in[1];
    const float* b1 = (const float*)d_in[2];
    const float* w2 = (const float*)d_in[3];
    const float* b2 = (const float*)d_in[4];
    const float* rw = (const float*)d_in[5];
    const float* rb = (const float*)d_in[6];
    float* out = (float*)d_out;

    const size_t contrib_elems = (size_t)NE * NB * NT * ND;           // 16 MiB
    const size_t gates_elems   = (size_t)NB * NT * NE;
    const size_t aux_elems     = 512;
    const size_t ws_need = (contrib_elems + gates_elems + aux_elems) * sizeof(float);

    if (ws_size >= ws_need) {
        float* contrib = (float*)d_ws;
        float* gates   = contrib + contrib_elems;
        float* auxp    = gates + gates_elems;

        moe_gates<<<512, 256, 0, stream>>>(x, rw, rb, gates, auxp);
        moe_main<<<NT * NE, 256, 0, stream>>>(x, w1, b1, w2, b2, gates, contrib);
        moe_reduce<<<(NB * NT * ND / 4) / 256, 256, 0, stream>>>(contrib, auxp, out);
    } else {
        hipMemsetAsync(d_out, 0, (size_t)(NB * NT * ND + 1) * sizeof(float), stream);
        moe_main_fb<<<NT * NE, 256, 0, stream>>>(x, w1, b1, w2, b2, rw, rb, out);
    }
}